// Round 1
// 325.367 us; speedup vs baseline: 1.0390x; 1.0390x over previous
//
#include <hip/hip_runtime.h>

// ---------------------------------------------------------------------------
// Tensor_CSPNet forward, restructured:
//   out[b,o] = sum_h <G[o,h], log(V_h^T X[b,h] V_h + D_h)> + const[o]
// ReEig stages are provably no-ops (all eigenvalues >= 0.5 >> 1e-4).
// Eigensolve: one-sided Hestenes Jacobi, pair-per-lane in registers,
// 16-lane groups (11 active), DPP circle-method migration.
// R16: prep rewrite. The old prep ran a SERIAL wave-0 Jacobi on bn/rm
// (minsweep 3, eps 1e-7 -> ~4 sweeps x 21 chained rotations with
// rcp/sqrt/rsq transcendental chains) on ONE wave per block -- a
// latency-bound ~100us critical path (bench 338us vs main 228us).
// Replaced with block-parallel coupled Newton-Schulz for bn^{1/2} and
// rm^{-1/2}:  Y<-0.5*Y*(3I-ZY), Z<-0.5*(3I-ZY)*Z  on A/||A||_F
// (lambda' in (0,1] -> guaranteed quadratic convergence; lambda'min
// >= ~0.04 -> <1e-8 by iter 9; K=11 fixed, no convergence check).
// All 256 threads do 22x22 LDS matmuls (v2f column pairs). Only
// S = rm^{-1/2} @ bn^{1/2} is consumed downstream, so the norm scales
// fold into one sqrt(c_bn/c_rm) factor on S.
// main_kernel: frozen R12/R13 measured-best (untouched).
// ---------------------------------------------------------------------------

#define WS_CONST 484                     // 4     : fc_w@conv_b + fc_b
#define WS_VT    512                     // 27*484: Vt[h][j][k] = V_h[k][j]
#define WS_V     (512 + 13068)           // 27*528: V[h][k][j], rows padded to 24
#define WS_D     (13580 + 14256)         // 27*484: D_h row-major (sym)
#define WS_G     (27836 + 13068)         // 4*27*528: G[o][h], rows padded to 24
#define G_STRIDE 528
#define V_STRIDE 528

typedef float v2f __attribute__((ext_vector_type(2)));

static __device__ __forceinline__ float dpp_shl1(float x) { // lane m <- lane m+1 (within 16-row)
  return __int_as_float(__builtin_amdgcn_mov_dpp(__float_as_int(x), 0x101, 0xf, 0xf, true));
}
static __device__ __forceinline__ float dpp_shr1(float x) { // lane m <- lane m-1 (within 16-row)
  return __int_as_float(__builtin_amdgcn_mov_dpp(__float_as_int(x), 0x111, 0xf, 0xf, true));
}

// one-sided Jacobi sweeps on column pairs held in registers (16-lane groups,
// lanes 0..10 active). Per-matrix convergence: offF2 = sum over the sweep's
// 231 pair-tests of d^2; exit at sweep s>=minsweep if previous sweep had
// offF2 <= eps2 * sum(lambda_i^2) for ALL 4 matrices in the wave.
static __device__ __forceinline__ void jacobi_sweeps(v2f wl[11], v2f wr[11],
                                                     bool is0, bool is10, bool inert,
                                                     int minsweep, float eps2) {
  int okprev = 0;
  #pragma unroll 1
  for (int sweep = 0; sweep < 5; ++sweep) {
    if (sweep >= minsweep && __all(okprev)) break;
    // fresh norms each sweep
    v2f na = (v2f)(0.f), nb = (v2f)(0.f);
    #pragma unroll
    for (int i = 0; i < 11; ++i) { na += wl[i]*wl[i]; nb += wr[i]*wr[i]; }
    float nL = na.x + na.y, nR = nb.x + nb.y;
    // Q = sum lambda_i^4 over the group's 22 columns (inert lanes gated out)
    float q = inert ? 0.f : (nL*nL + nR*nR);
    q += __shfl_xor(q, 1, 16);
    q += __shfl_xor(q, 2, 16);
    q += __shfl_xor(q, 4, 16);
    q += __shfl_xor(q, 8, 16);
    float dacc = 0.f;
    #pragma unroll 1
    for (int r = 0; r < 21; ++r) {
      v2f da = (v2f)(0.f), db = (v2f)(0.f);
      #pragma unroll
      for (int i = 0; i < 10; i += 2) { da += wl[i]*wr[i]; db += wl[i+1]*wr[i+1]; }
      da += wl[10]*wr[10];
      float d = (da.x + da.y) + (db.x + db.y);
      dacc += d*d;
      // R9 rotation math (measured fastest): tau chain
      float ad  = fabsf(d);
      float tau = (nR - nL)*0.5f*__builtin_amdgcn_rcpf(d);
      float sq  = sqrtf(1.0f + tau*tau);
      float t   = copysignf(__builtin_amdgcn_rcpf(fabsf(tau) + sq), tau);
      float c   = __builtin_amdgcn_rsqf(1.0f + t*t);
      float s   = t*c;
      bool tiny = (ad < 1e-28f);
      c = tiny ? 1.0f : c;
      s = tiny ? 0.0f : s;
      float cc = c*c, ss = s*s, cs2 = 2.0f*c*s;
      float nLn = cc*nL - cs2*d + ss*nR;
      float nRn = ss*nL + cs2*d + cc*nR;
      v2f cv = (v2f)(c), sv = (v2f)(s);
      #pragma unroll
      for (int i = 0; i < 11; ++i) {
        v2f nl = cv*wl[i] - sv*wr[i];
        v2f nr = sv*wl[i] + cv*wr[i];
        float tlx = dpp_shl1(nl.x), tly = dpp_shl1(nl.y);
        float trx = dpp_shr1(nr.x), trY = dpp_shr1(nr.y);
        wl[i].x = is0 ? nl.x : (is10 ? nr.x : tlx);
        wl[i].y = is0 ? nl.y : (is10 ? nr.y : tly);
        wr[i].x = is0 ? tlx : trx;
        wr[i].y = is0 ? tly : trY;
      }
      {
        float tl = dpp_shl1(nLn), tr = dpp_shr1(nRn);
        nL = is0 ? nLn : (is10 ? nRn : tl);
        nR = is0 ? tl : tr;
      }
    }
    float ds = inert ? 0.f : dacc;     // gate junk/NaN AFTER accumulation
    ds += __shfl_xor(ds, 1, 16);
    ds += __shfl_xor(ds, 2, 16);
    ds += __shfl_xor(ds, 4, 16);
    ds += __shfl_xor(ds, 8, 16);
    okprev = (ds <= eps2*q);
  }
}

// ---------------- prep: NS(bn,rm) -> S -> per-h Vt, V, D, G ----------------
// Coupled Newton-Schulz (all 256 threads, LDS matmuls):
//   A' = A/||A||_F ; Y0=A', Z0=I
//   T = 3I - Z@Y ; Y <- 0.5*Y@T ; Z <- 0.5*T@Z     (K=11 iterations)
//   Y -> A'^{1/2}, Z -> A'^{-1/2}
// S = rm^{-1/2} @ bn^{1/2} = sqrt(c_bn/c_rm) * Z_rm @ Y_bn.
__global__ void prep_kernel(const float* __restrict__ rm, const float* __restrict__ bn,
                            const float* __restrict__ W1, const float* __restrict__ W2,
                            const float* __restrict__ conv_w, const float* __restrict__ fc_w,
                            const float* __restrict__ conv_b, const float* __restrict__ fc_b,
                            float* __restrict__ ws, float* __restrict__ out) {
  __shared__ float sW1[1024] __attribute__((aligned(16)));
  __shared__ float sW2[704]  __attribute__((aligned(16)));
  __shared__ float sY[2][2][484] __attribute__((aligned(16)));  // [mat][buf][..]
  __shared__ float sZ[2][2][484] __attribute__((aligned(16)));
  __shared__ float sT[2][484]    __attribute__((aligned(16)));
  __shared__ float sS[484]  __attribute__((aligned(16)));
  __shared__ float sU[704]  __attribute__((aligned(16)));
  __shared__ float sE[220]  __attribute__((aligned(16)));
  __shared__ float sG[1936] __attribute__((aligned(16)));
  __shared__ float sC[2];
  const int tid = threadIdx.x, h = blockIdx.x;

  if (h == 0)  // zero the atomic-add target (replaces memset dispatch)
    for (int idx = tid; idx < 2048; idx += 256) out[idx] = 0.f;

  // phase A: waves 0/1 compute Frobenius norms of bn/rm; waves 2/3 stage W1,W2
  const int wv = tid >> 6, ln = tid & 63;
  if (wv < 2) {
    const float* src = wv ? rm : bn;
    float s = 0.f;
    for (int i = ln; i < 484; i += 64) { float v = src[i]; s += v*v; }
    s += __shfl_xor(s, 1);  s += __shfl_xor(s, 2);  s += __shfl_xor(s, 4);
    s += __shfl_xor(s, 8);  s += __shfl_xor(s, 16); s += __shfl_xor(s, 32);
    if (ln == 0) sC[wv] = sqrtf(s);
  } else {
    const int t = tid - 128;
    for (int i = t; i < 1024; i += 128) sW1[i] = W1[h*1024 + i];
    for (int i = t; i < 704;  i += 128) sW2[i] = W2[h*704 + i];
  }
  __syncthreads();

  // phase B: init Y = A/c, Z = I for both matrices
  {
    const float ic0 = 1.0f/sC[0], ic1 = 1.0f/sC[1];
    for (int idx = tid; idx < 484; idx += 256) {
      const int i = idx/22, j = idx - 22*i;
      const float e = (i == j) ? 1.f : 0.f;
      sY[0][0][idx] = bn[idx]*ic0;  sZ[0][0][idx] = e;
      sY[1][0][idx] = rm[idx]*ic1;  sZ[1][0][idx] = e;
    }
  }
  __syncthreads();

  // phase C: K=11 coupled NS iterations (v2f column pairs: 22 rows x 11 pairs)
  int cur = 0;
  #pragma unroll 1
  for (int it = 0; it < 11; ++it) {
    // T = 3I - Z@Y (both matrices: 484 v2f elements)
    for (int idx = tid; idx < 484; idx += 256) {
      const int mt = (idx >= 242), r = idx - mt*242, i = r/11, jp = r - 11*i;
      const float* Zc = sZ[mt][cur];
      const float* Yc = sY[mt][cur];
      v2f acc = (v2f)(0.f);
      #pragma unroll
      for (int k = 0; k < 22; ++k)
        acc += *(const v2f*)(Yc + k*22 + 2*jp) * Zc[i*22 + k];
      v2f tv;
      tv.x = ((2*jp     == i) ? 3.f : 0.f) - acc.x;
      tv.y = ((2*jp + 1 == i) ? 3.f : 0.f) - acc.y;
      *(v2f*)(sT[mt] + i*22 + 2*jp) = tv;
    }
    __syncthreads();
    // Ynew = 0.5*Y@T ; Znew = 0.5*T@Z  (968 v2f elements)
    for (int idx = tid; idx < 968; idx += 256) {
      const int sel = idx/242, r = idx - 242*sel, i = r/11, jp = r - 11*i;
      const int mt = sel >> 1; const bool isZ = sel & 1;
      const float* A = isZ ? sT[mt] : sY[mt][cur];
      const float* B = isZ ? sZ[mt][cur] : sT[mt];
      v2f acc = (v2f)(0.f);
      #pragma unroll
      for (int k = 0; k < 22; ++k)
        acc += *(const v2f*)(B + k*22 + 2*jp) * A[i*22 + k];
      *(v2f*)((isZ ? sZ[mt][cur^1] : sY[mt][cur^1]) + i*22 + 2*jp) = 0.5f*acc;
    }
    __syncthreads();
    cur ^= 1;   // data now lives in buffer 'cur'
  }

  // phase D: S = sqrt(c_bn/c_rm)*Z_rm@Y_bn ; U = W1@W2 ; raw G (independent)
  {
    const float scale = sqrtf(sC[0]/sC[1]);
    const float* Zrm = sZ[1][cur];
    const float* Ybn = sY[0][cur];
    for (int idx = tid; idx < 484; idx += 256) {
      const int i = idx/22, j = idx - 22*i;
      float s = 0.f;
      for (int k = 0; k < 22; ++k) s += Zrm[i*22+k]*Ybn[k*22+j];
      sS[idx] = scale*s;
    }
  }
  for (int idx = tid; idx < 704; idx += 256) {
    const int n = idx/22, j = idx - 22*n;
    float s = 0.f;
    for (int k = 0; k < 32; ++k) s += sW1[n*32+k]*sW2[k*22+j];
    sU[idx] = s;
  }
  {
    const int wi = h/9, bi = h - 9*wi;
    for (int idx = tid; idx < 1936; idx += 256) {
      const int o = idx/484, r = idx - 484*o;
      float s = 0.f;
      for (int c = 0; c < 48; ++c) s += fc_w[o*48+c]*conv_w[c*13068 + wi*4356 + bi*484 + r];
      sG[idx] = s;
    }
  }
  __syncthreads();

  // V = U_top @ S: write transposed (Vt, packed) and row-major (stride 24)
  for (int idx = tid; idx < 484; idx += 256) {
    const int k = idx/22, j = idx - 22*k;
    float s = 0.f;
    for (int l = 0; l < 22; ++l) s += sU[k*22+l]*sS[l*22+j];
    ws[WS_VT + h*484 + j*22 + k] = s;
    ws[WS_V  + h*V_STRIDE + k*24 + j] = s;
  }
  // E = U_bot @ S (10x22)
  for (int idx = tid; idx < 220; idx += 256) {
    const int e = idx/22, j = idx - 22*e;
    float s = 0.f;
    for (int l = 0; l < 22; ++l) s += sU[(22+e)*22+l]*sS[l*22+j];
    sE[idx] = s;
  }
  __syncthreads();
  // D = E^T E (22x22, symmetric)
  for (int idx = tid; idx < 484; idx += 256) {
    const int i = idx/22, j = idx - 22*i;
    float s = 0.f;
    for (int e = 0; e < 10; ++e) s += sE[e*22+i]*sE[e*22+j];
    ws[WS_D + h*484 + idx] = s;
  }
  // G symmetrized into padded layout
  for (int idx = tid; idx < 1936; idx += 256) {
    const int o = idx/484, r = idx - 484*o, i = r/22, j = r - 22*i;
    const float v = 0.5f*(sG[o*484 + i*22 + j] + sG[o*484 + j*22 + i]);
    ws[WS_G + (o*27+h)*G_STRIDE + i*24 + j] = v;
  }
  if (h == 0 && tid < 4) {
    float s = 0.f;
    for (int c = 0; c < 48; ++c) s += fc_w[tid*48+c]*conv_b[c];
    ws[WS_CONST + tid] = s + fc_b[tid];
  }
}

// ---------------- main: P4 build + one-sided Jacobi + projection -----------
// h is wave-uniform -> V/D/G base pointers uniform -> scalar loads (SMEM).
// Zero LDS; 64-thread blocks (4 matrices) for even CU balance.
__global__ void __launch_bounds__(64, 3) main_kernel(const float* __restrict__ x,
                                                     const float* __restrict__ ws,
                                                     float* __restrict__ out) {
  const int lane = threadIdx.x;
  const int g = lane >> 4, m = lane & 15;
  const int mm = (m < 10) ? m : 10;          // lanes 11..15 mirror pair 10 (inert)
  const int h  = blockIdx.x % 27;            // wave-uniform
  const int b  = (blockIdx.x/27)*4 + g;
  const int id = b*27 + h;                   // matrix index in x

  // V column pair 2mm, 2mm+1 (rows 2mm,2mm+1 of Vt; 44 contiguous floats)
  v2f vl[11], vrr[11];
  {
    const v2f* vb = (const v2f*)(ws + WS_VT + h*484 + mm*44);
    #pragma unroll
    for (int j = 0; j < 11; ++j) { vl[j] = vb[j]; vrr[j] = vb[11+j]; }
  }
  // init w = D rows 2mm, 2mm+1 (columns of symmetric D)
  v2f wl[11], wr[11];
  {
    const v2f* d2 = (const v2f*)(ws + WS_D + h*484 + mm*44);
    #pragma unroll
    for (int j = 0; j < 11; ++j) { wl[j] = d2[j]; wr[j] = d2[11+j]; }
  }
  // streamed build: for each row k, t_k = <Xrow_k, v>, then w += V[k][:] * t_k
  {
    const v2f* X2 = (const v2f*)(x + (size_t)id * 484);
    const float* Vrow = ws + WS_V + h*V_STRIDE;
    #pragma unroll 2
    for (int k = 0; k < 22; ++k) {
      v2f aL = (v2f)(0.f), aR = (v2f)(0.f);
      #pragma unroll
      for (int c = 0; c < 11; ++c) {
        v2f xv = X2[11*k + c];
        aL += xv*vl[c];
        aR += xv*vrr[c];
      }
      float tLk = aL.x + aL.y, tRk = aR.x + aR.y;
      const v2f* vk = (const v2f*)(Vrow + k*24);
      #pragma unroll
      for (int j = 0; j < 11; ++j) {
        v2f q = vk[j];
        wl[j] += q*tLk;
        wr[j] += q*tRk;
      }
    }
  }

  jacobi_sweeps(wl, wr, (m == 0), (m == 10), (m > 10), 2, 1e-4f);

  // log-eig coefficients: L = sum_j (log lam_j / lam_j^2) w_j w_j^T, lam^2 = ||w||^2
  float nL, nR;
  {
    v2f na = (v2f)(0.f), nb = (v2f)(0.f);
    #pragma unroll
    for (int i = 0; i < 11; ++i) { na += wl[i]*wl[i]; nb += wr[i]*wr[i]; }
    nL = na.x + na.y; nR = nb.x + nb.y;
  }
  const float HALF_LN2 = 0.34657359f;        // 0.5*ln(2)
  float coefL = HALF_LN2*log2f(fmaxf(nL, 1e-8f))*__builtin_amdgcn_rcpf(nL);
  float coefR = HALF_LN2*log2f(fmaxf(nR, 1e-8f))*__builtin_amdgcn_rcpf(nR);

  // projection: out[b,o] += sum_cols coef * (w^T G[o,h] w)
  #pragma unroll 1
  for (int o = 0; o < 4; ++o) {
    const float* Gptr = ws + WS_G + (o*27+h)*G_STRIDE;
    float qL = 0.f, qR = 0.f;
    #pragma unroll
    for (int k = 0; k < 22; ++k) {
      const v2f* g2 = (const v2f*)(Gptr + k*24);
      v2f sa = (v2f)(0.f), ra = (v2f)(0.f);
      #pragma unroll
      for (int j = 0; j < 11; ++j) {
        v2f q = g2[j];
        sa += q*wl[j];
        ra += q*wr[j];
      }
      float wLk = wl[k>>1][k&1], wRk = wr[k>>1][k&1];
      qL += wLk*(sa.x + sa.y);
      qR += wRk*(ra.x + ra.y);
    }
    float v = (m <= 10) ? (coefL*qL + coefR*qR) : 0.0f;
    v += __shfl_down(v, 8, 16);
    v += __shfl_down(v, 4, 16);
    v += __shfl_down(v, 2, 16);
    v += __shfl_down(v, 1, 16);
    if (m == 0) {
      if (h == 0) v += ws[WS_CONST + o];
      atomicAdd(out + b*4 + o, v);
    }
  }
}

extern "C" void kernel_launch(void* const* d_in, const int* in_sizes, int n_in,
                              void* d_out, int out_size, void* d_ws, size_t ws_size,
                              hipStream_t stream) {
  const float* x   = (const float*)d_in[0];
  const float* W1  = (const float*)d_in[1];
  const float* W2  = (const float*)d_in[2];
  const float* rm  = (const float*)d_in[3];
  const float* bn  = (const float*)d_in[4];
  const float* cw  = (const float*)d_in[5];
  const float* cb  = (const float*)d_in[6];
  const float* fw  = (const float*)d_in[7];
  const float* fb  = (const float*)d_in[8];
  float* out = (float*)d_out;
  float* ws  = (float*)d_ws;

  prep_kernel<<<27, 256, 0, stream>>>(rm, bn, W1, W2, cw, fw, cb, fb, ws, out);
  main_kernel<<<3456, 64, 0, stream>>>(x, ws, out);
}

// Round 2
// 316.628 us; speedup vs baseline: 1.0676x; 1.0276x over previous
//
#include <hip/hip_runtime.h>

// ---------------------------------------------------------------------------
// Tensor_CSPNet forward, restructured:
//   out[b,o] = sum_h <G[o,h], log(V_h^T X[b,h] V_h + D_h)> + const[o]
// ReEig stages are provably no-ops (all eigenvalues >= 0.5 >> 1e-4).
// Eigensolve: one-sided Hestenes Jacobi, pair-per-lane in registers,
// 16-lane groups (11 active), DPP circle-method migration.
// R16: prep Jacobi(bn,rm) -> block-parallel coupled Newton-Schulz (-13us).
// R17: prep G-pass rewrite. Old: per-element 48-term dot, c-major ->
// 52KB-stride cold loads, fc_w as vector loads, 4x re-fetch of conv_w,
// ~8 latency-serialized outer iters/thread on a 27-block grid (no TLP).
// New: thread t owns v2f r=2t; 48 coalesced strided v2f loads (242
// lanes x 8B contiguous per c), 4x register reuse across o, fc_w via
// wave-uniform s_loads. If total doesn't move, gap = harness overhead
// and the next lever is main occupancy, not prep.
// main_kernel: frozen R12/R13 measured-best (untouched).
// ---------------------------------------------------------------------------

#define WS_CONST 484                     // 4     : fc_w@conv_b + fc_b
#define WS_VT    512                     // 27*484: Vt[h][j][k] = V_h[k][j]
#define WS_V     (512 + 13068)           // 27*528: V[h][k][j], rows padded to 24
#define WS_D     (13580 + 14256)         // 27*484: D_h row-major (sym)
#define WS_G     (27836 + 13068)         // 4*27*528: G[o][h], rows padded to 24
#define G_STRIDE 528
#define V_STRIDE 528

typedef float v2f __attribute__((ext_vector_type(2)));

static __device__ __forceinline__ float dpp_shl1(float x) { // lane m <- lane m+1 (within 16-row)
  return __int_as_float(__builtin_amdgcn_mov_dpp(__float_as_int(x), 0x101, 0xf, 0xf, true));
}
static __device__ __forceinline__ float dpp_shr1(float x) { // lane m <- lane m-1 (within 16-row)
  return __int_as_float(__builtin_amdgcn_mov_dpp(__float_as_int(x), 0x111, 0xf, 0xf, true));
}

// one-sided Jacobi sweeps on column pairs held in registers (16-lane groups,
// lanes 0..10 active). Per-matrix convergence: offF2 = sum over the sweep's
// 231 pair-tests of d^2; exit at sweep s>=minsweep if previous sweep had
// offF2 <= eps2 * sum(lambda_i^2) for ALL 4 matrices in the wave.
static __device__ __forceinline__ void jacobi_sweeps(v2f wl[11], v2f wr[11],
                                                     bool is0, bool is10, bool inert,
                                                     int minsweep, float eps2) {
  int okprev = 0;
  #pragma unroll 1
  for (int sweep = 0; sweep < 5; ++sweep) {
    if (sweep >= minsweep && __all(okprev)) break;
    // fresh norms each sweep
    v2f na = (v2f)(0.f), nb = (v2f)(0.f);
    #pragma unroll
    for (int i = 0; i < 11; ++i) { na += wl[i]*wl[i]; nb += wr[i]*wr[i]; }
    float nL = na.x + na.y, nR = nb.x + nb.y;
    // Q = sum lambda_i^4 over the group's 22 columns (inert lanes gated out)
    float q = inert ? 0.f : (nL*nL + nR*nR);
    q += __shfl_xor(q, 1, 16);
    q += __shfl_xor(q, 2, 16);
    q += __shfl_xor(q, 4, 16);
    q += __shfl_xor(q, 8, 16);
    float dacc = 0.f;
    #pragma unroll 1
    for (int r = 0; r < 21; ++r) {
      v2f da = (v2f)(0.f), db = (v2f)(0.f);
      #pragma unroll
      for (int i = 0; i < 10; i += 2) { da += wl[i]*wr[i]; db += wl[i+1]*wr[i+1]; }
      da += wl[10]*wr[10];
      float d = (da.x + da.y) + (db.x + db.y);
      dacc += d*d;
      // R9 rotation math (measured fastest): tau chain
      float ad  = fabsf(d);
      float tau = (nR - nL)*0.5f*__builtin_amdgcn_rcpf(d);
      float sq  = sqrtf(1.0f + tau*tau);
      float t   = copysignf(__builtin_amdgcn_rcpf(fabsf(tau) + sq), tau);
      float c   = __builtin_amdgcn_rsqf(1.0f + t*t);
      float s   = t*c;
      bool tiny = (ad < 1e-28f);
      c = tiny ? 1.0f : c;
      s = tiny ? 0.0f : s;
      float cc = c*c, ss = s*s, cs2 = 2.0f*c*s;
      float nLn = cc*nL - cs2*d + ss*nR;
      float nRn = ss*nL + cs2*d + cc*nR;
      v2f cv = (v2f)(c), sv = (v2f)(s);
      #pragma unroll
      for (int i = 0; i < 11; ++i) {
        v2f nl = cv*wl[i] - sv*wr[i];
        v2f nr = sv*wl[i] + cv*wr[i];
        float tlx = dpp_shl1(nl.x), tly = dpp_shl1(nl.y);
        float trx = dpp_shr1(nr.x), trY = dpp_shr1(nr.y);
        wl[i].x = is0 ? nl.x : (is10 ? nr.x : tlx);
        wl[i].y = is0 ? nl.y : (is10 ? nr.y : tly);
        wr[i].x = is0 ? tlx : trx;
        wr[i].y = is0 ? tly : trY;
      }
      {
        float tl = dpp_shl1(nLn), tr = dpp_shr1(nRn);
        nL = is0 ? nLn : (is10 ? nRn : tl);
        nR = is0 ? tl : tr;
      }
    }
    float ds = inert ? 0.f : dacc;     // gate junk/NaN AFTER accumulation
    ds += __shfl_xor(ds, 1, 16);
    ds += __shfl_xor(ds, 2, 16);
    ds += __shfl_xor(ds, 4, 16);
    ds += __shfl_xor(ds, 8, 16);
    okprev = (ds <= eps2*q);
  }
}

// ---------------- prep: NS(bn,rm) -> S -> per-h Vt, V, D, G ----------------
// Coupled Newton-Schulz (all 256 threads, LDS matmuls):
//   A' = A/||A||_F ; Y0=A', Z0=I
//   T = 3I - Z@Y ; Y <- 0.5*Y@T ; Z <- 0.5*T@Z     (K=11 iterations)
//   Y -> A'^{1/2}, Z -> A'^{-1/2}
// S = rm^{-1/2} @ bn^{1/2} = sqrt(c_bn/c_rm) * Z_rm @ Y_bn.
__global__ void prep_kernel(const float* __restrict__ rm, const float* __restrict__ bn,
                            const float* __restrict__ W1, const float* __restrict__ W2,
                            const float* __restrict__ conv_w, const float* __restrict__ fc_w,
                            const float* __restrict__ conv_b, const float* __restrict__ fc_b,
                            float* __restrict__ ws, float* __restrict__ out) {
  __shared__ float sW1[1024] __attribute__((aligned(16)));
  __shared__ float sW2[704]  __attribute__((aligned(16)));
  __shared__ float sY[2][2][484] __attribute__((aligned(16)));  // [mat][buf][..]
  __shared__ float sZ[2][2][484] __attribute__((aligned(16)));
  __shared__ float sT[2][484]    __attribute__((aligned(16)));
  __shared__ float sS[484]  __attribute__((aligned(16)));
  __shared__ float sU[704]  __attribute__((aligned(16)));
  __shared__ float sE[220]  __attribute__((aligned(16)));
  __shared__ float sG[1936] __attribute__((aligned(16)));
  __shared__ float sC[2];
  const int tid = threadIdx.x, h = blockIdx.x;

  if (h == 0)  // zero the atomic-add target (replaces memset dispatch)
    for (int idx = tid; idx < 2048; idx += 256) out[idx] = 0.f;

  // phase A: waves 0/1 compute Frobenius norms of bn/rm; waves 2/3 stage W1,W2
  const int wv = tid >> 6, ln = tid & 63;
  if (wv < 2) {
    const float* src = wv ? rm : bn;
    float s = 0.f;
    for (int i = ln; i < 484; i += 64) { float v = src[i]; s += v*v; }
    s += __shfl_xor(s, 1);  s += __shfl_xor(s, 2);  s += __shfl_xor(s, 4);
    s += __shfl_xor(s, 8);  s += __shfl_xor(s, 16); s += __shfl_xor(s, 32);
    if (ln == 0) sC[wv] = sqrtf(s);
  } else {
    const int t = tid - 128;
    for (int i = t; i < 1024; i += 128) sW1[i] = W1[h*1024 + i];
    for (int i = t; i < 704;  i += 128) sW2[i] = W2[h*704 + i];
  }
  __syncthreads();

  // phase B: init Y = A/c, Z = I for both matrices
  {
    const float ic0 = 1.0f/sC[0], ic1 = 1.0f/sC[1];
    for (int idx = tid; idx < 484; idx += 256) {
      const int i = idx/22, j = idx - 22*i;
      const float e = (i == j) ? 1.f : 0.f;
      sY[0][0][idx] = bn[idx]*ic0;  sZ[0][0][idx] = e;
      sY[1][0][idx] = rm[idx]*ic1;  sZ[1][0][idx] = e;
    }
  }
  __syncthreads();

  // phase C: K=11 coupled NS iterations (v2f column pairs: 22 rows x 11 pairs)
  int cur = 0;
  #pragma unroll 1
  for (int it = 0; it < 11; ++it) {
    // T = 3I - Z@Y (both matrices: 484 v2f elements)
    for (int idx = tid; idx < 484; idx += 256) {
      const int mt = (idx >= 242), r = idx - mt*242, i = r/11, jp = r - 11*i;
      const float* Zc = sZ[mt][cur];
      const float* Yc = sY[mt][cur];
      v2f acc = (v2f)(0.f);
      #pragma unroll
      for (int k = 0; k < 22; ++k)
        acc += *(const v2f*)(Yc + k*22 + 2*jp) * Zc[i*22 + k];
      v2f tv;
      tv.x = ((2*jp     == i) ? 3.f : 0.f) - acc.x;
      tv.y = ((2*jp + 1 == i) ? 3.f : 0.f) - acc.y;
      *(v2f*)(sT[mt] + i*22 + 2*jp) = tv;
    }
    __syncthreads();
    // Ynew = 0.5*Y@T ; Znew = 0.5*T@Z  (968 v2f elements)
    for (int idx = tid; idx < 968; idx += 256) {
      const int sel = idx/242, r = idx - 242*sel, i = r/11, jp = r - 11*i;
      const int mt = sel >> 1; const bool isZ = sel & 1;
      const float* A = isZ ? sT[mt] : sY[mt][cur];
      const float* B = isZ ? sZ[mt][cur] : sT[mt];
      v2f acc = (v2f)(0.f);
      #pragma unroll
      for (int k = 0; k < 22; ++k)
        acc += *(const v2f*)(B + k*22 + 2*jp) * A[i*22 + k];
      *(v2f*)((isZ ? sZ[mt][cur^1] : sY[mt][cur^1]) + i*22 + 2*jp) = 0.5f*acc;
    }
    __syncthreads();
    cur ^= 1;   // data now lives in buffer 'cur'
  }

  // phase D: S = sqrt(c_bn/c_rm)*Z_rm@Y_bn ; U = W1@W2 ; raw G (coalesced)
  {
    const float scale = sqrtf(sC[0]/sC[1]);
    const float* Zrm = sZ[1][cur];
    const float* Ybn = sY[0][cur];
    for (int idx = tid; idx < 484; idx += 256) {
      const int i = idx/22, j = idx - 22*i;
      float s = 0.f;
      for (int k = 0; k < 22; ++k) s += Zrm[i*22+k]*Ybn[k*22+j];
      sS[idx] = scale*s;
    }
  }
  for (int idx = tid; idx < 704; idx += 256) {
    const int n = idx/22, j = idx - 22*n;
    float s = 0.f;
    for (int k = 0; k < 32; ++k) s += sW1[n*32+k]*sW2[k*22+j];
    sU[idx] = s;
  }
  // raw G, coalesced: thread t owns v2f element r = 2t,2t+1 of all 4 outputs.
  // 48 in-flight strided v2f loads (lanes contiguous per c), 4x register
  // reuse across o; fc_w indices are wave-uniform literals -> s_loads.
  if (tid < 242) {
    const int wi = h/9, bi = h - 9*wi;
    const float* base = conv_w + wi*4356 + bi*484 + 2*tid;
    v2f a0 = (v2f)(0.f), a1 = (v2f)(0.f), a2 = (v2f)(0.f), a3 = (v2f)(0.f);
    #pragma unroll
    for (int c = 0; c < 48; ++c) {
      const v2f wv2 = *(const v2f*)(base + c*13068);
      a0 += wv2*fc_w[c];
      a1 += wv2*fc_w[48+c];
      a2 += wv2*fc_w[96+c];
      a3 += wv2*fc_w[144+c];
    }
    *(v2f*)(sG +        2*tid) = a0;
    *(v2f*)(sG +  484 + 2*tid) = a1;
    *(v2f*)(sG +  968 + 2*tid) = a2;
    *(v2f*)(sG + 1452 + 2*tid) = a3;
  }
  __syncthreads();

  // V = U_top @ S: write transposed (Vt, packed) and row-major (stride 24)
  for (int idx = tid; idx < 484; idx += 256) {
    const int k = idx/22, j = idx - 22*k;
    float s = 0.f;
    for (int l = 0; l < 22; ++l) s += sU[k*22+l]*sS[l*22+j];
    ws[WS_VT + h*484 + j*22 + k] = s;
    ws[WS_V  + h*V_STRIDE + k*24 + j] = s;
  }
  // E = U_bot @ S (10x22)
  for (int idx = tid; idx < 220; idx += 256) {
    const int e = idx/22, j = idx - 22*e;
    float s = 0.f;
    for (int l = 0; l < 22; ++l) s += sU[(22+e)*22+l]*sS[l*22+j];
    sE[idx] = s;
  }
  __syncthreads();
  // D = E^T E (22x22, symmetric)
  for (int idx = tid; idx < 484; idx += 256) {
    const int i = idx/22, j = idx - 22*i;
    float s = 0.f;
    for (int e = 0; e < 10; ++e) s += sE[e*22+i]*sE[e*22+j];
    ws[WS_D + h*484 + idx] = s;
  }
  // G symmetrized into padded layout
  for (int idx = tid; idx < 1936; idx += 256) {
    const int o = idx/484, r = idx - 484*o, i = r/22, j = r - 22*i;
    const float v = 0.5f*(sG[o*484 + i*22 + j] + sG[o*484 + j*22 + i]);
    ws[WS_G + (o*27+h)*G_STRIDE + i*24 + j] = v;
  }
  if (h == 0 && tid < 4) {
    float s = 0.f;
    for (int c = 0; c < 48; ++c) s += fc_w[tid*48+c]*conv_b[c];
    ws[WS_CONST + tid] = s + fc_b[tid];
  }
}

// ---------------- main: P4 build + one-sided Jacobi + projection -----------
// h is wave-uniform -> V/D/G base pointers uniform -> scalar loads (SMEM).
// Zero LDS; 64-thread blocks (4 matrices) for even CU balance.
__global__ void __launch_bounds__(64, 3) main_kernel(const float* __restrict__ x,
                                                     const float* __restrict__ ws,
                                                     float* __restrict__ out) {
  const int lane = threadIdx.x;
  const int g = lane >> 4, m = lane & 15;
  const int mm = (m < 10) ? m : 10;          // lanes 11..15 mirror pair 10 (inert)
  const int h  = blockIdx.x % 27;            // wave-uniform
  const int b  = (blockIdx.x/27)*4 + g;
  const int id = b*27 + h;                   // matrix index in x

  // V column pair 2mm, 2mm+1 (rows 2mm,2mm+1 of Vt; 44 contiguous floats)
  v2f vl[11], vrr[11];
  {
    const v2f* vb = (const v2f*)(ws + WS_VT + h*484 + mm*44);
    #pragma unroll
    for (int j = 0; j < 11; ++j) { vl[j] = vb[j]; vrr[j] = vb[11+j]; }
  }
  // init w = D rows 2mm, 2mm+1 (columns of symmetric D)
  v2f wl[11], wr[11];
  {
    const v2f* d2 = (const v2f*)(ws + WS_D + h*484 + mm*44);
    #pragma unroll
    for (int j = 0; j < 11; ++j) { wl[j] = d2[j]; wr[j] = d2[11+j]; }
  }
  // streamed build: for each row k, t_k = <Xrow_k, v>, then w += V[k][:] * t_k
  {
    const v2f* X2 = (const v2f*)(x + (size_t)id * 484);
    const float* Vrow = ws + WS_V + h*V_STRIDE;
    #pragma unroll 2
    for (int k = 0; k < 22; ++k) {
      v2f aL = (v2f)(0.f), aR = (v2f)(0.f);
      #pragma unroll
      for (int c = 0; c < 11; ++c) {
        v2f xv = X2[11*k + c];
        aL += xv*vl[c];
        aR += xv*vrr[c];
      }
      float tLk = aL.x + aL.y, tRk = aR.x + aR.y;
      const v2f* vk = (const v2f*)(Vrow + k*24);
      #pragma unroll
      for (int j = 0; j < 11; ++j) {
        v2f q = vk[j];
        wl[j] += q*tLk;
        wr[j] += q*tRk;
      }
    }
  }

  jacobi_sweeps(wl, wr, (m == 0), (m == 10), (m > 10), 2, 1e-4f);

  // log-eig coefficients: L = sum_j (log lam_j / lam_j^2) w_j w_j^T, lam^2 = ||w||^2
  float nL, nR;
  {
    v2f na = (v2f)(0.f), nb = (v2f)(0.f);
    #pragma unroll
    for (int i = 0; i < 11; ++i) { na += wl[i]*wl[i]; nb += wr[i]*wr[i]; }
    nL = na.x + na.y; nR = nb.x + nb.y;
  }
  const float HALF_LN2 = 0.34657359f;        // 0.5*ln(2)
  float coefL = HALF_LN2*log2f(fmaxf(nL, 1e-8f))*__builtin_amdgcn_rcpf(nL);
  float coefR = HALF_LN2*log2f(fmaxf(nR, 1e-8f))*__builtin_amdgcn_rcpf(nR);

  // projection: out[b,o] += sum_cols coef * (w^T G[o,h] w)
  #pragma unroll 1
  for (int o = 0; o < 4; ++o) {
    const float* Gptr = ws + WS_G + (o*27+h)*G_STRIDE;
    float qL = 0.f, qR = 0.f;
    #pragma unroll
    for (int k = 0; k < 22; ++k) {
      const v2f* g2 = (const v2f*)(Gptr + k*24);
      v2f sa = (v2f)(0.f), ra = (v2f)(0.f);
      #pragma unroll
      for (int j = 0; j < 11; ++j) {
        v2f q = g2[j];
        sa += q*wl[j];
        ra += q*wr[j];
      }
      float wLk = wl[k>>1][k&1], wRk = wr[k>>1][k&1];
      qL += wLk*(sa.x + sa.y);
      qR += wRk*(ra.x + ra.y);
    }
    float v = (m <= 10) ? (coefL*qL + coefR*qR) : 0.0f;
    v += __shfl_down(v, 8, 16);
    v += __shfl_down(v, 4, 16);
    v += __shfl_down(v, 2, 16);
    v += __shfl_down(v, 1, 16);
    if (m == 0) {
      if (h == 0) v += ws[WS_CONST + o];
      atomicAdd(out + b*4 + o, v);
    }
  }
}

extern "C" void kernel_launch(void* const* d_in, const int* in_sizes, int n_in,
                              void* d_out, int out_size, void* d_ws, size_t ws_size,
                              hipStream_t stream) {
  const float* x   = (const float*)d_in[0];
  const float* W1  = (const float*)d_in[1];
  const float* W2  = (const float*)d_in[2];
  const float* rm  = (const float*)d_in[3];
  const float* bn  = (const float*)d_in[4];
  const float* cw  = (const float*)d_in[5];
  const float* cb  = (const float*)d_in[6];
  const float* fw  = (const float*)d_in[7];
  const float* fb  = (const float*)d_in[8];
  float* out = (float*)d_out;
  float* ws  = (float*)d_ws;

  prep_kernel<<<27, 256, 0, stream>>>(rm, bn, W1, W2, cw, fw, cb, fb, ws, out);
  main_kernel<<<3456, 64, 0, stream>>>(x, ws, out);
}